// Round 15
// baseline (4060.015 us; speedup 1.0000x reference)
//
#include <hip/hip_runtime.h>

// CustomGRU: B=256, T=1024, I=128, H=256.  out = concat(output[B,T,H], h_last[B,H]) f32.
//
// R15 = R14 with the h-layout map fixed: hpos(k) = k + 4*(k>>5)  (injective; R14's
// k + 4*((k>>5)&1) collided on [60,68) and corrupted 4 units/64 every step).
// Structure: packed-u64 exchange (data+version, one L2 RTT), 2 units x 8k per
// thread, W in 48 pinned regs, v_pk_fma_f32 matvec, XOR-indexed butterfly reduce.

#define B_SZ 256
#define T_SZ 1024
#define H_SZ 256
#define G3   768
#define NGRP 32
#define SPIN_MAX (1 << 27)
#define HROW 288

typedef __attribute__((ext_vector_type(2))) float f32x2;

template<int CTRL>
__device__ __forceinline__ float dppx(float s) {
    return __int_as_float(
        __builtin_amdgcn_update_dpp(0, __float_as_int(s), CTRL, 0xF, 0xF, true));
}
template<int MASK>
__device__ __forceinline__ float swzx(float s) {
    return __int_as_float(__builtin_amdgcn_ds_swizzle(__float_as_int(s), MASK));
}
__device__ __forceinline__ f32x2 pkfma(f32x2 a, f32x2 b, f32x2 c) {
    f32x2 d;
    asm("v_pk_fma_f32 %0, %1, %2, %3" : "=v"(d) : "v"(a), "v"(b), "v"(c));
    return d;
}

// h position map: word k -> k + 4*(k>>5)  (4-word pad per 32; injective, max 283)
static __device__ __forceinline__ int hpos(int k) { return k + 4 * (k >> 5); }

// slot: [g 32][par 2][n 8][unit 256] u64 = (ver<<32)|f32bits
static __device__ __forceinline__ size_t xsl(int g, int par, int n, int u) {
    return (((size_t)g * 2 + par) * 8 + n) * 256 + u;
}

// ---------------- prep ----------------
__global__ void prep_kernel(const float* __restrict__ h0,
                            unsigned long long* __restrict__ xch) {
    int tid = blockIdx.x * blockDim.x + threadIdx.x;
    if (tid < B_SZ * H_SZ) {
        int b = tid >> 8, u = tid & 255;
        int g = b >> 3, n = b & 7;
        unsigned long long val = (unsigned long long)__float_as_uint(h0[tid]);
        xch[xsl(g, 0, n, u)] = val;
        xch[xsl(g, 1, n, u)] = val;
    }
}

// ---------------- phase 1: gx = x @ W_ih^T (unchanged since R9) ----------------
__global__ __launch_bounds__(256) void gemm_x_kernel(
    const float* __restrict__ x, const float* __restrict__ wih,
    float* __restrict__ gx, int c, int tcShift)
{
    __shared__ __align__(16) float xs[64][132];
    __shared__ __align__(16) float ws[128][68];
    const int TC = 1 << tcShift;
    const int t  = threadIdx.x;
    const int bx = blockIdx.x, by = blockIdx.y;

#pragma unroll
    for (int i = 0; i < 8; ++i) {
        int f4 = t + i * 256;
        int r  = f4 >> 5, c4 = (f4 & 31) * 4;
        int rho = bx * 64 + r;
        int b = rho >> tcShift, u = rho & (TC - 1);
        float4 v = *(const float4*)(x + ((size_t)b * T_SZ + (size_t)c * TC + u) * 128 + c4);
        *(float4*)&xs[r][c4] = v;
    }

    const int gl = t & 31;
    const int rl = t >> 5;
    float acc[8][4];
#pragma unroll
    for (int i = 0; i < 8; ++i)
#pragma unroll
        for (int jj = 0; jj < 4; ++jj) acc[i][jj] = 0.f;

    for (int kb = 0; kb < 2; ++kb) {
        __syncthreads();
#pragma unroll
        for (int i = 0; i < 8; ++i) {
            int f4 = t + i * 256;
            int row = f4 >> 4, c4 = (f4 & 15) * 4;
            float4 v = *(const float4*)(wih + (size_t)(by * 128 + row) * 128 + kb * 64 + c4);
            *(float4*)&ws[row][c4] = v;
        }
        __syncthreads();

#pragma unroll 4
        for (int k4 = 0; k4 < 16; ++k4) {
            float4 wv0 = *(const float4*)&ws[gl     ][k4 * 4];
            float4 wv1 = *(const float4*)&ws[gl + 32][k4 * 4];
            float4 wv2 = *(const float4*)&ws[gl + 64][k4 * 4];
            float4 wv3 = *(const float4*)&ws[gl + 96][k4 * 4];
#pragma unroll
            for (int rr = 0; rr < 8; ++rr) {
                float4 xv = *(const float4*)&xs[rl + rr * 8][kb * 64 + k4 * 4];
                acc[rr][0] = fmaf(xv.w, wv0.w, fmaf(xv.z, wv0.z, fmaf(xv.y, wv0.y, fmaf(xv.x, wv0.x, acc[rr][0]))));
                acc[rr][1] = fmaf(xv.w, wv1.w, fmaf(xv.z, wv1.z, fmaf(xv.y, wv1.y, fmaf(xv.x, wv1.x, acc[rr][1]))));
                acc[rr][2] = fmaf(xv.w, wv2.w, fmaf(xv.z, wv2.z, fmaf(xv.y, wv2.y, fmaf(xv.x, wv2.x, acc[rr][2]))));
                acc[rr][3] = fmaf(xv.w, wv3.w, fmaf(xv.z, wv3.z, fmaf(xv.y, wv3.y, fmaf(xv.x, wv3.x, acc[rr][3]))));
            }
        }
    }

#pragma unroll
    for (int rr = 0; rr < 8; ++rr) {
        size_t base = (size_t)(bx * 64 + rl + rr * 8) * G3 + by * 128 + gl;
#pragma unroll
        for (int gi = 0; gi < 4; ++gi)
            gx[base + 32 * gi] = acc[rr][gi];
    }
}

#define PIN2(v) asm volatile("" : "+v"(v));

// ---------------- phase 2: recurrence ----------------
// grid 256 x 512. g = bid&31, w = bid>>5, u0 = 32w. Thread: j2 = t>>5 (unit pair),
// p = t&31 (8-k slice). fam = {uaR,uaZ,uaN,ubR,ubZ,ubN}; s[fam][i] = batch i^(p&7).
__global__ __launch_bounds__(512)
__attribute__((amdgpu_waves_per_eu(2, 2)))
void gru_kernel(
    const float* __restrict__ gx, const float* __restrict__ whh,
    const float* __restrict__ bih, const float* __restrict__ bhh,
    unsigned long long* __restrict__ xch, float* __restrict__ out,
    int gbase, int tc, int isLast)
{
    __shared__ __align__(16) float hl[8][HROW];
    __shared__ __align__(16) float hst[8][32];

    const int t   = threadIdx.x;
    const int bid = blockIdx.x;
    const int g   = bid & 31;
    const int w   = bid >> 5;
    const int u0  = w * 32;
    const int j2  = t >> 5;
    const int p   = t & 31;
    const int pb  = p & 7;
    const int ua  = u0 + 2 * j2;
    const int ub  = ua + 1;
    const int k0  = 8 * p;

    // ---- W: 6 families x 4 f32x2 = 48 f32 (pinned as pairs for pk_fma) ----
    f32x2 wf[6][4];
    {
        const int rows[6] = {ua, 256 + ua, 512 + ua, ub, 256 + ub, 512 + ub};
#pragma unroll
        for (int f = 0; f < 6; ++f) {
            float4 va = *(const float4*)(whh + (size_t)rows[f] * H_SZ + k0);
            float4 vb = *(const float4*)(whh + (size_t)rows[f] * H_SZ + k0 + 4);
            wf[f][0] = (f32x2){va.x, va.y};
            wf[f][1] = (f32x2){va.z, va.w};
            wf[f][2] = (f32x2){vb.x, vb.y};
            wf[f][3] = (f32x2){vb.z, vb.w};
        }
    }
#pragma unroll
    for (int f = 0; f < 6; ++f) {
        PIN2(wf[f][0]) PIN2(wf[f][1]) PIN2(wf[f][2]) PIN2(wf[f][3])
    }

    const float bsrA = bih[ua]       + bhh[ua];
    const float bszA = bih[256 + ua] + bhh[256 + ua];
    const float bsnA = bih[512 + ua] + bhh[512 + ua];
    const float bsrB = bih[ub]       + bhh[ub];
    const float bszB = bih[256 + ub] + bhh[256 + ub];
    const float bsnB = bih[512 + ub] + bhh[512 + ub];

    const float* gxp = (p < 8) ? gx + ((size_t)(8 * g + p) * tc) * G3 + ua : nullptr;

    // gather mapping: thread polls 4 slots (batch n_t, units 4m..4m+3)
    const int n_t = t >> 6;
    const int m   = t & 63;
    const int wofs = 4 * m + 4 * (m >> 3);         // = hpos(4m)
    // matvec read base word offset for this lane's k-slice
    const int Wd = hpos(k0);
    // matvec row pointers (row i^pb), hoisted across the whole step loop
    const float* hrow[8];
#pragma unroll
    for (int i = 0; i < 8; ++i) hrow[i] = &hl[i ^ pb][Wd];
    const int pua = hpos(ua);
    // out-store mapping (t<64)
    const int n_o = t >> 3, f_o = t & 7;

    // preload gx(u=0)
    float gxrA = 0.f, gxzA = 0.f, gxnA = 0.f, gxrB = 0.f, gxzB = 0.f, gxnB = 0.f;
    if (p < 8) {
        gxrA = gxp[0];   gxzA = gxp[256]; gxnA = gxp[512];
        gxrB = gxp[1];   gxzB = gxp[257]; gxnB = gxp[513];
    }

#pragma unroll 1
    for (int u = 0; u < tc; ++u) {
        const int tg  = gbase + u;
        const int par = tg & 1;

        // ---- coalesced out-store for step u-1 (hst stable since last barrier) ----
        if (u > 0 && t < 64) {
            float4 o;
            o.x = hst[n_o][4 * f_o];     o.y = hst[n_o][4 * f_o + 1];
            o.z = hst[n_o][4 * f_o + 2]; o.w = hst[n_o][4 * f_o + 3];
            *(float4*)(out + ((size_t)(8 * g + n_o) * T_SZ + (tg - 1)) * H_SZ + u0 + 4 * f_o) = o;
        }

        // ---- gather h(tg): poll 4 packed slots ----
        {
            unsigned long long* sb = xch + xsl(g, par, n_t, 4 * m);
            const unsigned want = (unsigned)tg;
            unsigned long long v0, v1, v2, v3;
            int sp = 0;
            for (;;) {
                v0 = __hip_atomic_load(sb + 0, __ATOMIC_RELAXED, __HIP_MEMORY_SCOPE_AGENT);
                v1 = __hip_atomic_load(sb + 1, __ATOMIC_RELAXED, __HIP_MEMORY_SCOPE_AGENT);
                v2 = __hip_atomic_load(sb + 2, __ATOMIC_RELAXED, __HIP_MEMORY_SCOPE_AGENT);
                v3 = __hip_atomic_load(sb + 3, __ATOMIC_RELAXED, __HIP_MEMORY_SCOPE_AGENT);
                bool ok = ((unsigned)(v0 >> 32) == want) & ((unsigned)(v1 >> 32) == want) &
                          ((unsigned)(v2 >> 32) == want) & ((unsigned)(v3 >> 32) == want);
                if (ok || ++sp >= SPIN_MAX) break;
                __builtin_amdgcn_s_sleep(2);
            }
            float4 hv;
            hv.x = __uint_as_float((unsigned)v0);
            hv.y = __uint_as_float((unsigned)v1);
            hv.z = __uint_as_float((unsigned)v2);
            hv.w = __uint_as_float((unsigned)v3);
            *(float4*)&hl[n_t][wofs] = hv;
        }
        __syncthreads();

        // ---- prefetch gx(u+1) ----
        float pgrA = 0.f, pgzA = 0.f, pgnA = 0.f, pgrB = 0.f, pgzB = 0.f, pgnB = 0.f;
        if (p < 8 && u + 1 < tc) {
            size_t go = (size_t)(u + 1) * G3;
            pgrA = gxp[go];     pgzA = gxp[go + 256]; pgnA = gxp[go + 512];
            pgrB = gxp[go + 1]; pgzB = gxp[go + 257]; pgnB = gxp[go + 513];
        }

        // ---- matvec: per batch-index i (batch n = i^pb), 24 pk_fma -> scalar ----
        float s0[8], s1[8], s2[8], s3[8], s4[8], s5[8];
#pragma unroll
        for (int i = 0; i < 8; ++i) {
            const float* hr = hrow[i];
            float4 hv0 = *(const float4*)(hr);
            float4 hv1 = *(const float4*)(hr + 4);
            f32x2 h0 = (f32x2){hv0.x, hv0.y};
            f32x2 h1 = (f32x2){hv0.z, hv0.w};
            f32x2 h2 = (f32x2){hv1.x, hv1.y};
            f32x2 h3 = (f32x2){hv1.z, hv1.w};
            f32x2 z = (f32x2){0.f, 0.f};
            f32x2 a0 = pkfma(h0, wf[0][0], pkfma(h1, wf[0][1], pkfma(h2, wf[0][2], pkfma(h3, wf[0][3], z))));
            f32x2 a1 = pkfma(h0, wf[1][0], pkfma(h1, wf[1][1], pkfma(h2, wf[1][2], pkfma(h3, wf[1][3], z))));
            f32x2 a2 = pkfma(h0, wf[2][0], pkfma(h1, wf[2][1], pkfma(h2, wf[2][2], pkfma(h3, wf[2][3], z))));
            f32x2 a3 = pkfma(h0, wf[3][0], pkfma(h1, wf[3][1], pkfma(h2, wf[3][2], pkfma(h3, wf[3][3], z))));
            f32x2 a4 = pkfma(h0, wf[4][0], pkfma(h1, wf[4][1], pkfma(h2, wf[4][2], pkfma(h3, wf[4][3], z))));
            f32x2 a5 = pkfma(h0, wf[5][0], pkfma(h1, wf[5][1], pkfma(h2, wf[5][2], pkfma(h3, wf[5][3], z))));
            s0[i] = a0.x + a0.y; s1[i] = a1.x + a1.y; s2[i] = a2.x + a2.y;
            s3[i] = a3.x + a3.y; s4[i] = a4.x + a4.y; s5[i] = a5.x + a5.y;
        }

        // ---- XOR-indexed butterfly (no selects) ----
        // stage xor1 (lane^1): combine into even i
#pragma unroll
        for (int i = 0; i < 8; i += 2) {
            s0[i] += dppx<0xB1>(s0[i ^ 1]); s1[i] += dppx<0xB1>(s1[i ^ 1]);
            s2[i] += dppx<0xB1>(s2[i ^ 1]); s3[i] += dppx<0xB1>(s3[i ^ 1]);
            s4[i] += dppx<0xB1>(s4[i ^ 1]); s5[i] += dppx<0xB1>(s5[i ^ 1]);
        }
        // stage xor2 (lane^2): into i in {0,4}
#pragma unroll
        for (int i = 0; i < 8; i += 4) {
            s0[i] += dppx<0x4E>(s0[i ^ 2]); s1[i] += dppx<0x4E>(s1[i ^ 2]);
            s2[i] += dppx<0x4E>(s2[i ^ 2]); s3[i] += dppx<0x4E>(s3[i ^ 2]);
            s4[i] += dppx<0x4E>(s4[i ^ 2]); s5[i] += dppx<0x4E>(s5[i ^ 2]);
        }
        // stage xor4 (lane^4, ds_swizzle): into i = 0
        s0[0] += swzx<0x101F>(s0[4]); s1[0] += swzx<0x101F>(s1[4]);
        s2[0] += swzx<0x101F>(s2[4]); s3[0] += swzx<0x101F>(s3[4]);
        s4[0] += swzx<0x101F>(s4[4]); s5[0] += swzx<0x101F>(s5[4]);
        // stage xor8 (row_ror:8): same batch both sides
        s0[0] += dppx<0x128>(s0[0]); s1[0] += dppx<0x128>(s1[0]);
        s2[0] += dppx<0x128>(s2[0]); s3[0] += dppx<0x128>(s3[0]);
        s4[0] += dppx<0x128>(s4[0]); s5[0] += dppx<0x128>(s5[0]);
        // stage xor16 (ds_swizzle)
        s0[0] += swzx<0x401F>(s0[0]); s1[0] += swzx<0x401F>(s1[0]);
        s2[0] += swzx<0x401F>(s2[0]); s3[0] += swzx<0x401F>(s3[0]);
        s4[0] += swzx<0x401F>(s4[0]); s5[0] += swzx<0x401F>(s5[0]);

        // ---- gates + publish (p<8, batch n=p, units ua/ub) ----
        if (p < 8) {
            float holdA = hl[p][pua];
            float holdB = hl[p][pua + 1];
            float arA = s0[0] + gxrA + bsrA;
            float azA = s1[0] + gxzA + bszA;
            float anA = s2[0] + gxnA + bsnA;
            float arB = s3[0] + gxrB + bsrB;
            float azB = s4[0] + gxzB + bszB;
            float anB = s5[0] + gxnB + bsnB;
            float rA = 1.f / (1.f + expf(-arA));
            float zA = 1.f / (1.f + expf(-azA));
            float nA = tanhf(rA * anA);
            float rB = 1.f / (1.f + expf(-arB));
            float zB = 1.f / (1.f + expf(-azB));
            float nB = tanhf(rB * anB);
            float hnA = (1.f - zA) * holdA + zA * nA;
            float hnB = (1.f - zB) * holdB + zB * nB;

            hst[p][2 * j2]     = hnA;
            hst[p][2 * j2 + 1] = hnB;
            const unsigned long long ver = (unsigned long long)(unsigned)(tg + 1) << 32;
            const int par1 = (tg + 1) & 1;
            __hip_atomic_store(xch + xsl(g, par1, p, ua),
                               ver | (unsigned long long)__float_as_uint(hnA),
                               __ATOMIC_RELAXED, __HIP_MEMORY_SCOPE_AGENT);
            __hip_atomic_store(xch + xsl(g, par1, p, ub),
                               ver | (unsigned long long)__float_as_uint(hnB),
                               __ATOMIC_RELAXED, __HIP_MEMORY_SCOPE_AGENT);
        }
        gxrA = pgrA; gxzA = pgzA; gxnA = pgnA;
        gxrB = pgrB; gxzB = pgzB; gxnB = pgnB;
        __syncthreads();   // hl reads done; hst visible; publishes drained
    }

    // ---- flush last step's out row (+ h_last) ----
    if (t < 64) {
        float4 o;
        o.x = hst[n_o][4 * f_o];     o.y = hst[n_o][4 * f_o + 1];
        o.z = hst[n_o][4 * f_o + 2]; o.w = hst[n_o][4 * f_o + 3];
        *(float4*)(out + ((size_t)(8 * g + n_o) * T_SZ + (gbase + tc - 1)) * H_SZ + u0 + 4 * f_o) = o;
        if (isLast)
            *(float4*)(out + (size_t)B_SZ * T_SZ * H_SZ
                           + (size_t)(8 * g + n_o) * H_SZ + u0 + 4 * f_o) = o;
    }
}

// ---------------- host ----------------
extern "C" void kernel_launch(void* const* d_in, const int* in_sizes, int n_in,
                              void* d_out, int out_size, void* d_ws, size_t ws_size,
                              hipStream_t stream) {
    const float* x   = (const float*)d_in[0];
    const float* h0  = (const float*)d_in[1];
    const float* wih = (const float*)d_in[2];
    const float* whh = (const float*)d_in[3];
    const float* bih = (const float*)d_in[4];
    const float* bhh = (const float*)d_in[5];
    float* out = (float*)d_out;

    char* ws = (char*)d_ws;
    const size_t xchB = (size_t)NGRP * 2 * 8 * 256 * 8;   // 1 MiB
    unsigned long long* xch = (unsigned long long*)ws;
    float* gxb = (float*)(ws + xchB);

    int tcShift = 10;
    while (tcShift > 0 &&
           xchB + (786432ull << tcShift) > ws_size) --tcShift;
    const int TC  = 1 << tcShift;
    const int nCh = T_SZ / TC;

    prep_kernel<<<dim3(256), dim3(256), 0, stream>>>(h0, xch);
    for (int c = 0; c < nCh; ++c) {
        gemm_x_kernel<<<dim3(B_SZ * TC / 64, 6), dim3(256), 0, stream>>>(
            x, wih, gxb, c, tcShift);
        gru_kernel<<<dim3(B_SZ), dim3(512), 0, stream>>>(
            gxb, whh, bih, bhh, xch, out, c * TC, TC, (c == nCh - 1) ? 1 : 0);
    }
}

// Round 16
// 3642.003 us; speedup vs baseline: 1.1148x; 1.1148x over previous
//
#include <hip/hip_runtime.h>

// CustomGRU: B=256, T=1024, I=128, H=256.  out = concat(output[B,T,H], h_last[B,H]) f32.
//
// R16: 4-WG groups (64 groups x 4 members, same-XCD). WG = 4 batches x 64 units.
// Thread: 4-unit quad x 8-k slice -> W = 96 f32 in 48 pinned f32x2 (live ~190 < 256).
// Halves matvec LDS reads (8 b128), poll loads (2), and group fan-in (4) vs R15.
// Reduce: batch bits on lane bits {0,1} (dpp xor1/xor2 select), ror4+ror8 dpp coset
// sum (replaces xor4 swizzle), xor16 ds_swizzle. Packed-u64 parity exchange.

#define B_SZ 256
#define T_SZ 1024
#define H_SZ 256
#define G3   768
#define NGRP 64
#define SPIN_MAX (1 << 27)
#define HROW 288

typedef __attribute__((ext_vector_type(2))) float f32x2;

template<int CTRL>
__device__ __forceinline__ float dppx(float s) {
    return __int_as_float(
        __builtin_amdgcn_update_dpp(0, __float_as_int(s), CTRL, 0xF, 0xF, true));
}
template<int MASK>
__device__ __forceinline__ float swzx(float s) {
    return __int_as_float(__builtin_amdgcn_ds_swizzle(__float_as_int(s), MASK));
}
__device__ __forceinline__ f32x2 pkfma(f32x2 a, f32x2 b, f32x2 c) {
    f32x2 d;
    asm("v_pk_fma_f32 %0, %1, %2, %3" : "=v"(d) : "v"(a), "v"(b), "v"(c));
    return d;
}

// h position map: word k -> k + 4*(k>>5)  (injective; 4-word pad per 32 words)
static __device__ __forceinline__ int hpos(int k) { return k + 4 * (k >> 5); }

// slot: [g 64][par 2][n 4][unit 256] u64 = (ver<<32)|f32bits
static __device__ __forceinline__ size_t xsl(int g, int par, int n, int u) {
    return (((size_t)g * 2 + par) * 4 + n) * 256 + u;
}

// ---------------- prep ----------------
__global__ void prep_kernel(const float* __restrict__ h0,
                            unsigned long long* __restrict__ xch) {
    int tid = blockIdx.x * blockDim.x + threadIdx.x;
    if (tid < B_SZ * H_SZ) {
        int b = tid >> 8, u = tid & 255;
        int g = b >> 2, n = b & 3;
        unsigned long long val = (unsigned long long)__float_as_uint(h0[tid]);
        xch[xsl(g, 0, n, u)] = val;
        xch[xsl(g, 1, n, u)] = val;
    }
}

// ---------------- phase 1: gx = x @ W_ih^T (unchanged since R9) ----------------
__global__ __launch_bounds__(256) void gemm_x_kernel(
    const float* __restrict__ x, const float* __restrict__ wih,
    float* __restrict__ gx, int c, int tcShift)
{
    __shared__ __align__(16) float xs[64][132];
    __shared__ __align__(16) float ws[128][68];
    const int TC = 1 << tcShift;
    const int t  = threadIdx.x;
    const int bx = blockIdx.x, by = blockIdx.y;

#pragma unroll
    for (int i = 0; i < 8; ++i) {
        int f4 = t + i * 256;
        int r  = f4 >> 5, c4 = (f4 & 31) * 4;
        int rho = bx * 64 + r;
        int b = rho >> tcShift, u = rho & (TC - 1);
        float4 v = *(const float4*)(x + ((size_t)b * T_SZ + (size_t)c * TC + u) * 128 + c4);
        *(float4*)&xs[r][c4] = v;
    }

    const int gl = t & 31;
    const int rl = t >> 5;
    float acc[8][4];
#pragma unroll
    for (int i = 0; i < 8; ++i)
#pragma unroll
        for (int jj = 0; jj < 4; ++jj) acc[i][jj] = 0.f;

    for (int kb = 0; kb < 2; ++kb) {
        __syncthreads();
#pragma unroll
        for (int i = 0; i < 8; ++i) {
            int f4 = t + i * 256;
            int row = f4 >> 4, c4 = (f4 & 15) * 4;
            float4 v = *(const float4*)(wih + (size_t)(by * 128 + row) * 128 + kb * 64 + c4);
            *(float4*)&ws[row][c4] = v;
        }
        __syncthreads();

#pragma unroll 4
        for (int k4 = 0; k4 < 16; ++k4) {
            float4 wv0 = *(const float4*)&ws[gl     ][k4 * 4];
            float4 wv1 = *(const float4*)&ws[gl + 32][k4 * 4];
            float4 wv2 = *(const float4*)&ws[gl + 64][k4 * 4];
            float4 wv3 = *(const float4*)&ws[gl + 96][k4 * 4];
#pragma unroll
            for (int rr = 0; rr < 8; ++rr) {
                float4 xv = *(const float4*)&xs[rl + rr * 8][kb * 64 + k4 * 4];
                acc[rr][0] = fmaf(xv.w, wv0.w, fmaf(xv.z, wv0.z, fmaf(xv.y, wv0.y, fmaf(xv.x, wv0.x, acc[rr][0]))));
                acc[rr][1] = fmaf(xv.w, wv1.w, fmaf(xv.z, wv1.z, fmaf(xv.y, wv1.y, fmaf(xv.x, wv1.x, acc[rr][1]))));
                acc[rr][2] = fmaf(xv.w, wv2.w, fmaf(xv.z, wv2.z, fmaf(xv.y, wv2.y, fmaf(xv.x, wv2.x, acc[rr][2]))));
                acc[rr][3] = fmaf(xv.w, wv3.w, fmaf(xv.z, wv3.z, fmaf(xv.y, wv3.y, fmaf(xv.x, wv3.x, acc[rr][3]))));
            }
        }
    }

#pragma unroll
    for (int rr = 0; rr < 8; ++rr) {
        size_t base = (size_t)(bx * 64 + rl + rr * 8) * G3 + by * 128 + gl;
#pragma unroll
        for (int gi = 0; gi < 4; ++gi)
            gx[base + 32 * gi] = acc[rr][gi];
    }
}

#define PIN2(v) asm volatile("" : "+v"(v));

// ---------------- phase 2: recurrence ----------------
// grid 256 x 512. g = bid&63 (group), m = bid>>6 (member 0..3, same XCD), u0 = 64m.
// Thread: q = t>>5 (unit quad uq = u0+4q), p = t&31 (8-k slice), pb = p&3.
// fam = gate*4 + e (e = unit within quad). s[fam][i] = batch i^pb partial.
__global__ __launch_bounds__(512)
__attribute__((amdgpu_waves_per_eu(2, 2)))
void gru_kernel(
    const float* __restrict__ gx, const float* __restrict__ whh,
    const float* __restrict__ bih, const float* __restrict__ bhh,
    unsigned long long* __restrict__ xch, float* __restrict__ out,
    int gbase, int tc, int isLast)
{
    __shared__ __align__(16) float hl[4][HROW];
    __shared__ __align__(16) float hst[4][64];

    const int t   = threadIdx.x;
    const int bid = blockIdx.x;
    const int g   = bid & 63;
    const int m   = bid >> 6;
    const int u0  = m * 64;
    const int q   = t >> 5;
    const int p   = t & 31;
    const int pb  = p & 3;
    const int uq  = u0 + 4 * q;
    const int k0  = 8 * p;

    // ---- W: 12 fams (3 gates x 4 units) x 8 k = 48 pinned f32x2 ----
    f32x2 wf[12][4];
#pragma unroll
    for (int gate = 0; gate < 3; ++gate) {
#pragma unroll
        for (int e = 0; e < 4; ++e) {
            const float* wr = whh + (size_t)(gate * 256 + uq + e) * H_SZ + k0;
            float4 va = *(const float4*)(wr);
            float4 vb = *(const float4*)(wr + 4);
            wf[gate * 4 + e][0] = (f32x2){va.x, va.y};
            wf[gate * 4 + e][1] = (f32x2){va.z, va.w};
            wf[gate * 4 + e][2] = (f32x2){vb.x, vb.y};
            wf[gate * 4 + e][3] = (f32x2){vb.z, vb.w};
        }
    }
#pragma unroll
    for (int f = 0; f < 12; ++f) {
        PIN2(wf[f][0]) PIN2(wf[f][1]) PIN2(wf[f][2]) PIN2(wf[f][3])
    }

    // ---- gate-lane invariants: lanes p<4 (units uq,uq+1), p in 16..19 (uq+2,uq+3) ----
    const bool hi  = (p >= 16);
    const bool act = (p < 4) || (p >= 16 && p < 20);
    const int  ueA = uq + (hi ? 2 : 0);          // and ueB = ueA+1
    float bsrA = 0.f, bszA = 0.f, bsnA = 0.f, bsrB = 0.f, bszB = 0.f, bsnB = 0.f;
    const float* gxp = nullptr;
    if (act) {
        bsrA = bih[ueA]       + bhh[ueA];
        bszA = bih[256 + ueA] + bhh[256 + ueA];
        bsnA = bih[512 + ueA] + bhh[512 + ueA];
        bsrB = bih[ueA + 1]       + bhh[ueA + 1];
        bszB = bih[257 + ueA]     + bhh[257 + ueA];
        bsnB = bih[513 + ueA]     + bhh[513 + ueA];
        gxp = gx + ((size_t)(4 * g + pb) * tc) * G3 + ueA;
    }

    // gather mapping: thread polls 2 slots (batch n_t, units 2c2, 2c2+1)
    const int n_t  = t >> 7;
    const int c2   = t & 127;
    const int wofs = 2 * c2 + 4 * (c2 >> 4);     // = hpos(2*c2)
    // matvec row pointers (row i^pb), hoisted
    const int Wd = hpos(k0);
    const float* hrow[4];
#pragma unroll
    for (int i = 0; i < 4; ++i) hrow[i] = &hl[i ^ pb][Wd];
    const int pua = hpos(ueA);
    // out-store mapping (t<64)
    const int n_o = t >> 4, f_o = t & 15;

    // preload gx(u=0)
    float gxrA = 0.f, gxzA = 0.f, gxnA = 0.f, gxrB = 0.f, gxzB = 0.f, gxnB = 0.f;
    if (act) {
        gxrA = gxp[0]; gxzA = gxp[256]; gxnA = gxp[512];
        gxrB = gxp[1]; gxzB = gxp[257]; gxnB = gxp[513];
    }

#pragma unroll 1
    for (int u = 0; u < tc; ++u) {
        const int tg  = gbase + u;
        const int par = tg & 1;

        // ---- coalesced out-store for step u-1 ----
        if (u > 0 && t < 64) {
            float4 o;
            o.x = hst[n_o][4 * f_o];     o.y = hst[n_o][4 * f_o + 1];
            o.z = hst[n_o][4 * f_o + 2]; o.w = hst[n_o][4 * f_o + 3];
            *(float4*)(out + ((size_t)(4 * g + n_o) * T_SZ + (tg - 1)) * H_SZ + u0 + 4 * f_o) = o;
        }

        // ---- gather h(tg): poll 2 packed slots ----
        {
            unsigned long long* sb = xch + xsl(g, par, n_t, 2 * c2);
            const unsigned want = (unsigned)tg;
            unsigned long long v0, v1;
            int sp = 0;
            for (;;) {
                v0 = __hip_atomic_load(sb + 0, __ATOMIC_RELAXED, __HIP_MEMORY_SCOPE_AGENT);
                v1 = __hip_atomic_load(sb + 1, __ATOMIC_RELAXED, __HIP_MEMORY_SCOPE_AGENT);
                bool ok = ((unsigned)(v0 >> 32) == want) & ((unsigned)(v1 >> 32) == want);
                if (ok || ++sp >= SPIN_MAX) break;
                __builtin_amdgcn_s_sleep(1);
            }
            float2 hv;
            hv.x = __uint_as_float((unsigned)v0);
            hv.y = __uint_as_float((unsigned)v1);
            *(float2*)&hl[n_t][wofs] = hv;
        }
        __syncthreads();

        // ---- prefetch gx(u+1) ----
        float pgrA = 0.f, pgzA = 0.f, pgnA = 0.f, pgrB = 0.f, pgzB = 0.f, pgnB = 0.f;
        if (act && u + 1 < tc) {
            size_t go = (size_t)(u + 1) * G3;
            pgrA = gxp[go];     pgzA = gxp[go + 256]; pgnA = gxp[go + 512];
            pgrB = gxp[go + 1]; pgzB = gxp[go + 257]; pgnB = gxp[go + 513];
        }

        // ---- matvec: 8 b128 reads, 192 pk_fma ----
        float s[12][4];
#pragma unroll
        for (int i = 0; i < 4; ++i) {
            const float* hr = hrow[i];
            float4 hv0 = *(const float4*)(hr);
            float4 hv1 = *(const float4*)(hr + 4);
            f32x2 h0 = (f32x2){hv0.x, hv0.y};
            f32x2 h1 = (f32x2){hv0.z, hv0.w};
            f32x2 h2 = (f32x2){hv1.x, hv1.y};
            f32x2 h3 = (f32x2){hv1.z, hv1.w};
            f32x2 z  = (f32x2){0.f, 0.f};
#pragma unroll
            for (int f = 0; f < 12; ++f) {
                f32x2 a = pkfma(h0, wf[f][0],
                          pkfma(h1, wf[f][1],
                          pkfma(h2, wf[f][2],
                          pkfma(h3, wf[f][3], z))));
                s[f][i] = a.x + a.y;
            }
        }

        // ---- reduce: xor1,xor2 (dpp select) | ror4+ror8 (dpp coset) | xor16 (swz) ----
#pragma unroll
        for (int f = 0; f < 12; ++f) {
            s[f][0] += dppx<0xB1>(s[f][1]);
            s[f][2] += dppx<0xB1>(s[f][3]);
            s[f][0] += dppx<0x4E>(s[f][2]);
            s[f][0] += dppx<0x124>(s[f][0]);   // ror4
            s[f][0] += dppx<0x128>(s[f][0]);   // ror8
            s[f][0] += swzx<0x401F>(s[f][0]);  // xor16
        }

        // ---- gates + publish (active lanes: batch pb, units ueA, ueA+1) ----
        if (act) {
            float srA = hi ? s[2][0]  : s[0][0];
            float srB = hi ? s[3][0]  : s[1][0];
            float szA = hi ? s[6][0]  : s[4][0];
            float szB = hi ? s[7][0]  : s[5][0];
            float snA = hi ? s[10][0] : s[8][0];
            float snB = hi ? s[11][0] : s[9][0];

            float holdA = hl[pb][pua];
            float holdB = hl[pb][pua + 1];
            float arA = srA + gxrA + bsrA;
            float azA = szA + gxzA + bszA;
            float anA = snA + gxnA + bsnA;
            float arB = srB + gxrB + bsrB;
            float azB = szB + gxzB + bszB;
            float anB = snB + gxnB + bsnB;
            float rA = 1.f / (1.f + expf(-arA));
            float zA = 1.f / (1.f + expf(-azA));
            float nA = tanhf(rA * anA);
            float rB = 1.f / (1.f + expf(-arB));
            float zB = 1.f / (1.f + expf(-azB));
            float nB = tanhf(rB * anB);
            float hnA = (1.f - zA) * holdA + zA * nA;
            float hnB = (1.f - zB) * holdB + zB * nB;

            hst[pb][ueA - u0]     = hnA;
            hst[pb][ueA - u0 + 1] = hnB;
            const unsigned long long ver = (unsigned long long)(unsigned)(tg + 1) << 32;
            const int par1 = (tg + 1) & 1;
            __hip_atomic_store(xch + xsl(g, par1, pb, ueA),
                               ver | (unsigned long long)__float_as_uint(hnA),
                               __ATOMIC_RELAXED, __HIP_MEMORY_SCOPE_AGENT);
            __hip_atomic_store(xch + xsl(g, par1, pb, ueA + 1),
                               ver | (unsigned long long)__float_as_uint(hnB),
                               __ATOMIC_RELAXED, __HIP_MEMORY_SCOPE_AGENT);
        }
        gxrA = pgrA; gxzA = pgzA; gxnA = pgnA;
        gxrB = pgrB; gxzB = pgzB; gxnB = pgnB;
        __syncthreads();   // hl reads done; hst visible; publishes drained
    }

    // ---- flush last step's out row (+ h_last) ----
    if (t < 64) {
        float4 o;
        o.x = hst[n_o][4 * f_o];     o.y = hst[n_o][4 * f_o + 1];
        o.z = hst[n_o][4 * f_o + 2]; o.w = hst[n_o][4 * f_o + 3];
        *(float4*)(out + ((size_t)(4 * g + n_o) * T_SZ + (gbase + tc - 1)) * H_SZ + u0 + 4 * f_o) = o;
        if (isLast)
            *(float4*)(out + (size_t)B_SZ * T_SZ * H_SZ
                           + (size_t)(4 * g + n_o) * H_SZ + u0 + 4 * f_o) = o;
    }
}

// ---------------- host ----------------
extern "C" void kernel_launch(void* const* d_in, const int* in_sizes, int n_in,
                              void* d_out, int out_size, void* d_ws, size_t ws_size,
                              hipStream_t stream) {
    const float* x   = (const float*)d_in[0];
    const float* h0  = (const float*)d_in[1];
    const float* wih = (const float*)d_in[2];
    const float* whh = (const float*)d_in[3];
    const float* bih = (const float*)d_in[4];
    const float* bhh = (const float*)d_in[5];
    float* out = (float*)d_out;

    char* ws = (char*)d_ws;
    const size_t xchB = (size_t)NGRP * 2 * 4 * 256 * 8;   // 512 KiB
    unsigned long long* xch = (unsigned long long*)ws;
    float* gxb = (float*)(ws + xchB);

    int tcShift = 10;
    while (tcShift > 0 &&
           xchB + (786432ull << tcShift) > ws_size) --tcShift;
    const int TC  = 1 << tcShift;
    const int nCh = T_SZ / TC;

    prep_kernel<<<dim3(256), dim3(256), 0, stream>>>(h0, xch);
    for (int c = 0; c < nCh; ++c) {
        gemm_x_kernel<<<dim3(B_SZ * TC / 64, 6), dim3(256), 0, stream>>>(
            x, wih, gxb, c, tcShift);
        gru_kernel<<<dim3(B_SZ), dim3(512), 0, stream>>>(
            gxb, whh, bih, bhh, xch, out, c * TC, TC, (c == nCh - 1) ? 1 : 0);
    }
}